// Round 2
// baseline (1160.146 us; speedup 1.0000x reference)
//
#include <hip/hip_runtime.h>
#include <cstdint>
#include <cstddef>

#define DEVI __device__ __forceinline__

typedef __bf16 bf16x8 __attribute__((ext_vector_type(8)));
typedef float  floatx4 __attribute__((ext_vector_type(4)));
typedef unsigned short ushort4v __attribute__((ext_vector_type(4)));

constexpr int NHEAD = 6;
constexpr int CLF = 64, CHF = 192;
constexpr int IMG = 256;
constexpr int HW  = IMG * IMG;

// pitches (bf16 elements); rows stay 16B-aligned (pitch % 8 == 0)
constexpr int PQK = 40;   // K_h buffers + q/ao wave scratch (32+8)
constexpr int PVT = 72;   // V_h^T buffers (64+8)
constexpr int PP  = 72;   // P wave scratch + s_lf staging pitch
constexpr int PHF = 200;  // s_hf staging pitch (192+8)

// ---- attention-phase LDS layout (bytes) ----
constexpr int OFF_KH  = 0;       // 2 x (64*40*2)=5120  -> [0,10240)
constexpr int OFF_VH  = 10240;   // 2 x (32*72*2)=4608  -> [10240,19456)
constexpr int OFF_SCR = 19456;   // 4 waves x 3584      -> [19456,33792)
constexpr int SCR_W   = 3584;    // per wave: q/ao [0,1280) pitch40, P [1280,3584) pitch72
constexpr int OFF_RPB = 34816;   // 1350*2=2700         -> [34816,37516) (written after B3)
// ---- staging-phase aliases (dead after B3) ----
constexpr int OFF_LF  = 0;       // 64*72*2  = 9216
constexpr int OFF_HF  = 9216;    // 64*200*2 = 25600 -> ends 34816
constexpr int OFF_RED = 34816;   // 4*256*4 = 4096 -> 38912 (dead after B2; rpb overlaps later: OK)
constexpr int SMEM_BYTES = 38912; // x4 blocks/CU = 155648 <= 163840

DEVI unsigned short f2b(float f) {  // fp32 -> bf16 RNE
  unsigned u = __float_as_uint(f);
  u += 0x7fffu + ((u >> 16) & 1u);
  return (unsigned short)(u >> 16);
}
DEVI float b2f(unsigned short s) { return __uint_as_float(((unsigned)s) << 16); }

DEVI floatx4 mfma_bf16(bf16x8 a, bf16x8 b, floatx4 c) {
  return __builtin_amdgcn_mfma_f32_16x16x32_bf16(a, b, c, 0, 0, 0);
}

// ---- prep: W[k][n] fp32 -> W^T[n][k] bf16 into workspace ----
__global__ void wca_prep(const float* __restrict__ Wq, const float* __restrict__ Wk,
                         const float* __restrict__ Wv, const float* __restrict__ Wo,
                         unsigned short* __restrict__ wT) {
  int i = blockIdx.x * 256 + threadIdx.x;  // grid covers exactly 122880
  if (i < 12288) {                         // WqT: 192 x 64
    int n = i >> 6, k = i & 63;
    wT[i] = f2b(Wq[k * 192 + n]);
  } else if (i < 49152) {                  // WkT: 192 x 192
    int j = i - 12288, n = j / 192, k = j - n * 192;
    wT[i] = f2b(Wk[k * 192 + n]);
  } else if (i < 86016) {                  // WvT
    int j = i - 49152, n = j / 192, k = j - n * 192;
    wT[i] = f2b(Wv[k * 192 + n]);
  } else {                                 // WoT
    int j = i - 86016, n = j / 192, k = j - n * 192;
    wT[i] = f2b(Wo[k * 192 + n]);
  }
}

__global__ __launch_bounds__(256, 4) void wca_main(
    const float* __restrict__ ylf, const float* __restrict__ yhf,
    const float* __restrict__ glf, const float* __restrict__ blf,
    const float* __restrict__ ghf, const float* __restrict__ bhf,
    const float* __restrict__ bq,  const float* __restrict__ bv,
    const float* __restrict__ bo,  const float* __restrict__ rpb,
    const unsigned short* __restrict__ wT, float* __restrict__ out) {
  __shared__ __align__(16) char smem[SMEM_BYTES];
  unsigned short* s_lf  = (unsigned short*)(smem + OFF_LF);
  unsigned short* s_hf  = (unsigned short*)(smem + OFF_HF);
  unsigned short* s_rpb = (unsigned short*)(smem + OFF_RPB);
  float* s_red = (float*)(smem + OFF_RED);

  const int tid  = threadIdx.x;
  const int lane = tid & 63;
  const int wv   = tid >> 6;       // wave 0..3
  const int quad = lane >> 4;
  const int l16  = lane & 15;

  const int wid = blockIdx.x;      // 4096 windows
  const int b   = wid >> 10;
  const int wy  = (wid >> 5) & 31;
  const int wx  = wid & 31;
  const int h0  = wy << 3, w0 = wx << 3;

  const int t_own = tid & 63;      // token owned for load/stats
  const int cg    = tid >> 6;      // channel group (wave-uniform)
  const int tyl   = t_own >> 3, txl = t_own & 7;

  // ---- phase 1: load + LN stats ----
  float lfv[16], hfv[48];
  float ls = 0.f, l2 = 0.f, hs = 0.f, h2 = 0.f;
  {
    const float* p = ylf + ((size_t)(b * CLF + cg) * IMG + (h0 + tyl)) * IMG + (w0 + txl);
#pragma unroll
    for (int k = 0; k < 16; k++) {
      float v = p[(size_t)k * 4 * HW];
      lfv[k] = v; ls += v; l2 += v * v;
    }
  }
  {
    const float* p = yhf + ((size_t)(b * CHF + cg) * IMG + (h0 + tyl)) * IMG + (w0 + txl);
#pragma unroll
    for (int k = 0; k < 48; k++) {
      float v = p[(size_t)k * 4 * HW];
      hfv[k] = v; hs += v; h2 += v * v;
    }
  }
  s_red[0 * 256 + (cg << 6) + t_own] = ls;
  s_red[1 * 256 + (cg << 6) + t_own] = l2;
  s_red[2 * 256 + (cg << 6) + t_own] = hs;
  s_red[3 * 256 + (cg << 6) + t_own] = h2;
  __syncthreads();  // B1
  float su = 0.f, sq = 0.f, hu = 0.f, hq = 0.f;
#pragma unroll
  for (int g = 0; g < 4; g++) {
    su += s_red[0 * 256 + (g << 6) + t_own];
    sq += s_red[1 * 256 + (g << 6) + t_own];
    hu += s_red[2 * 256 + (g << 6) + t_own];
    hq += s_red[3 * 256 + (g << 6) + t_own];
  }
  const float mu_lf = su * (1.f / 64.f);
  const float rs_lf = rsqrtf(sq * (1.f / 64.f) - mu_lf * mu_lf + 1e-5f);
  const float mu_hf = hu * (1.f / 192.f);
  const float rs_hf = rsqrtf(hq * (1.f / 192.f) - mu_hf * mu_hf + 1e-5f);
#pragma unroll
  for (int k = 0; k < 16; k++) {
    int c = (k << 2) + cg;
    s_lf[t_own * PP + c] = f2b((lfv[k] - mu_lf) * rs_lf * glf[c] + blf[c]);
  }
#pragma unroll
  for (int k = 0; k < 48; k++) {
    int c = (k << 2) + cg;
    s_hf[t_own * PHF + c] = f2b((hfv[k] - mu_hf) * rs_hf * ghf[c] + bhf[c]);
  }
  __syncthreads();  // B2

  // ---- phase 2: own-row A-fragments into registers ----
  bf16x8 alf[2], ahf[6];
  {
    const unsigned short* rlf = s_lf + (wv * 16 + l16) * PP;
    alf[0] = *(const bf16x8*)(rlf + quad * 8);
    alf[1] = *(const bf16x8*)(rlf + 32 + quad * 8);
    const unsigned short* rhf = s_hf + (wv * 16 + l16) * PHF;
#pragma unroll
    for (int ks = 0; ks < 6; ks++) ahf[ks] = *(const bf16x8*)(rhf + ks * 32 + quad * 8);
  }
  __syncthreads();  // B3: staging region dead, attention buffers live

  // stage rpb (bf16); visible to readers after the h=0 barrier
  for (int i = tid; i < 225 * NHEAD; i += 256) s_rpb[i] = f2b(rpb[i]);

  const unsigned short* wqT = wT;           // [192][64]
  const unsigned short* wkT = wT + 12288;   // [192][192]
  const unsigned short* wvT = wT + 49152;
  const unsigned short* woT = wT + 86016;

  const int row_c = wv * 16 + quad * 4;     // C-layout absolute row base
  unsigned short* s_qa = (unsigned short*)(smem + OFF_SCR + wv * SCR_W);        // pitch 40
  unsigned short* s_pw = (unsigned short*)(smem + OFF_SCR + wv * SCR_W) + 640;  // pitch 72

  floatx4 oacc[12];
#pragma unroll
  for (int i = 0; i < 12; i++) oacc[i] = floatx4{0.f, 0.f, 0.f, 0.f};

  for (int h = 0; h < NHEAD; h++) {
    unsigned short* s_kh = (unsigned short*)(smem + OFF_KH + (h & 1) * 5120);
    unsigned short* s_vh = (unsigned short*)(smem + OFF_VH + (h & 1) * 4608);

    // K_h: own 16 rows x 32 (bk dropped: softmax-shift-invariant, exact)
#pragma unroll
    for (int ct = 0; ct < 2; ct++) {
      const int n = h * 32 + ct * 16 + l16;
      floatx4 acc = {0.f, 0.f, 0.f, 0.f};
#pragma unroll
      for (int ks = 0; ks < 6; ks++)
        acc = mfma_bf16(ahf[ks], *(const bf16x8*)(wkT + n * 192 + ks * 32 + quad * 8), acc);
#pragma unroll
      for (int r = 0; r < 4; r++)
        s_kh[(row_c + r) * PQK + ct * 16 + l16] = f2b(acc[r]);
    }
    // V_h: own 16 rows, stored transposed [d][token] (packed b64 writes)
#pragma unroll
    for (int ct = 0; ct < 2; ct++) {
      const int n = h * 32 + ct * 16 + l16;
      floatx4 acc = {0.f, 0.f, 0.f, 0.f};
#pragma unroll
      for (int ks = 0; ks < 6; ks++)
        acc = mfma_bf16(ahf[ks], *(const bf16x8*)(wvT + n * 192 + ks * 32 + quad * 8), acc);
      const float bvv = bv[n];
      ushort4v pk;
#pragma unroll
      for (int r = 0; r < 4; r++) pk[r] = f2b(acc[r] + bvv);
      *(ushort4v*)(s_vh + (ct * 16 + l16) * PVT + row_c) = pk;
    }
    // Q_h into wave-private scratch (C-layout -> A-layout transpose)
#pragma unroll
    for (int ct = 0; ct < 2; ct++) {
      const int n = h * 32 + ct * 16 + l16;
      floatx4 acc = {0.f, 0.f, 0.f, 0.f};
      acc = mfma_bf16(alf[0], *(const bf16x8*)(wqT + n * 64 + quad * 8), acc);
      acc = mfma_bf16(alf[1], *(const bf16x8*)(wqT + n * 64 + 32 + quad * 8), acc);
      const float bqv = bq[n];
#pragma unroll
      for (int r = 0; r < 4; r++)
        s_qa[(quad * 4 + r) * PQK + ct * 16 + l16] = f2b(acc[r] + bqv);
    }
    __syncthreads();  // per-head barrier: K_h/V_h (+rpb at h=0) visible

    // ---- S = Q K^T * scale + bias ----
    bf16x8 aq = *(const bf16x8*)(s_qa + l16 * PQK + quad * 8);
    float sv[4][4];
#pragma unroll
    for (int ct = 0; ct < 4; ct++) {
      bf16x8 kb = *(const bf16x8*)(s_kh + (ct * 16 + l16) * PQK + quad * 8);
      floatx4 acc = {0.f, 0.f, 0.f, 0.f};
      acc = mfma_bf16(aq, kb, acc);
#pragma unroll
      for (int r = 0; r < 4; r++) {
        const int row = row_c + r, col = ct * 16 + l16;
        const int dy = (row >> 3) - (col >> 3) + 7;
        const int dx = (row & 7) - (col & 7) + 7;
        sv[ct][r] = acc[r] * 0.17677669529663688f + b2f(s_rpb[(dy * 15 + dx) * NHEAD + h]);
      }
    }
    // ---- softmax over 64 keys (4 in-lane + xor-shuffle over 16 lanes) ----
#pragma unroll
    for (int r = 0; r < 4; r++) {
      float m = fmaxf(fmaxf(sv[0][r], sv[1][r]), fmaxf(sv[2][r], sv[3][r]));
      m = fmaxf(m, __shfl_xor(m, 1));
      m = fmaxf(m, __shfl_xor(m, 2));
      m = fmaxf(m, __shfl_xor(m, 4));
      m = fmaxf(m, __shfl_xor(m, 8));
      const float L2E = 1.4426950408889634f;
      float e0 = exp2f((sv[0][r] - m) * L2E);
      float e1 = exp2f((sv[1][r] - m) * L2E);
      float e2 = exp2f((sv[2][r] - m) * L2E);
      float e3 = exp2f((sv[3][r] - m) * L2E);
      float s = e0 + e1 + e2 + e3;
      s += __shfl_xor(s, 1);
      s += __shfl_xor(s, 2);
      s += __shfl_xor(s, 4);
      s += __shfl_xor(s, 8);
      float inv = 1.f / s;
      sv[0][r] = e0 * inv; sv[1][r] = e1 * inv; sv[2][r] = e2 * inv; sv[3][r] = e3 * inv;
    }
    // P into wave scratch (C -> A transpose), then PV
#pragma unroll
    for (int ct = 0; ct < 4; ct++)
#pragma unroll
      for (int r = 0; r < 4; r++)
        s_pw[(quad * 4 + r) * PP + ct * 16 + l16] = f2b(sv[ct][r]);
    bf16x8 pa0 = *(const bf16x8*)(s_pw + l16 * PP + quad * 8);
    bf16x8 pa1 = *(const bf16x8*)(s_pw + l16 * PP + 32 + quad * 8);
    floatx4 aoacc[2];
#pragma unroll
    for (int nt = 0; nt < 2; nt++) {
      floatx4 acc = {0.f, 0.f, 0.f, 0.f};
      acc = mfma_bf16(pa0, *(const bf16x8*)(s_vh + (nt * 16 + l16) * PVT + quad * 8), acc);
      acc = mfma_bf16(pa1, *(const bf16x8*)(s_vh + (nt * 16 + l16) * PVT + 32 + quad * 8), acc);
      aoacc[nt] = acc;
    }
    // ao_h C->A transpose through scratch (aliases Q slot: Q already consumed)
#pragma unroll
    for (int nt = 0; nt < 2; nt++)
#pragma unroll
      for (int r = 0; r < 4; r++)
        s_qa[(quad * 4 + r) * PQK + nt * 16 + l16] = f2b(aoacc[nt][r]);
    bf16x8 aoA = *(const bf16x8*)(s_qa + l16 * PQK + quad * 8);
    // O += ao_h @ Wo[h*32:(h+1)*32, :]
#pragma unroll
    for (int ct = 0; ct < 12; ct++)
      oacc[ct] = mfma_bf16(aoA, *(const bf16x8*)(woT + (ct * 16 + l16) * 192 + h * 32 + quad * 8),
                           oacc[ct]);
  }

  // ---- epilogue: direct float4 residual+store from C-layout (no barrier) ----
  const int tyo = wv * 2 + (quad >> 1);
  const int tx0 = (quad & 1) * 4;
#pragma unroll
  for (int ct = 0; ct < 12; ct++) {
    const int c = ct * 16 + l16;
    const float bov = bo[c];
    const size_t idx = ((size_t)(b * CHF + c) * IMG + (h0 + tyo)) * IMG + (w0 + tx0);
    const float4 res = *(const float4*)(yhf + idx);
    float4 o;
    o.x = oacc[ct][0] + bov + res.x;
    o.y = oacc[ct][1] + bov + res.y;
    o.z = oacc[ct][2] + bov + res.z;
    o.w = oacc[ct][3] + bov + res.w;
    *(float4*)(out + idx) = o;
  }
}

extern "C" void kernel_launch(void* const* d_in, const int* in_sizes, int n_in,
                              void* d_out, int out_size, void* d_ws, size_t ws_size,
                              hipStream_t stream) {
  const float* ylf = (const float*)d_in[0];
  const float* yhf = (const float*)d_in[1];
  const float* glf = (const float*)d_in[2];
  const float* blf = (const float*)d_in[3];
  const float* ghf = (const float*)d_in[4];
  const float* bhf = (const float*)d_in[5];
  const float* Wq  = (const float*)d_in[6];
  const float* bq  = (const float*)d_in[7];
  const float* Wk  = (const float*)d_in[8];
  // d_in[9] = bk: dropped (softmax-shift-invariant)
  const float* Wv  = (const float*)d_in[10];
  const float* bv  = (const float*)d_in[11];
  const float* Wo  = (const float*)d_in[12];
  const float* bo  = (const float*)d_in[13];
  const float* rpb = (const float*)d_in[14];
  unsigned short* wT = (unsigned short*)d_ws;  // 122880 bf16 = 245760 B

  wca_prep<<<480, 256, 0, stream>>>(Wq, Wk, Wv, Wo, wT);
  wca_main<<<4096, 256, 0, stream>>>(ylf, yhf, glf, blf, ghf, bhf,
                                     bq, bv, bo, rpb, wT, (float*)d_out);
}